// Round 1
// baseline (786.153 us; speedup 1.0000x reference)
//
#include <hip/hip_runtime.h>
#include <math.h>

#define HCH 32
#define NIR 16
#define DF 512

__device__ __constant__ int c_lidx[16] = {0,1,1,1,2,2,2,2,2,3,3,3,3,3,3,3};

// K1: per-edge spherical harmonics Y[E][16]
__global__ void k_edge_sh(const float* __restrict__ pos,
                          const int* __restrict__ src,
                          const int* __restrict__ dst,
                          const float* __restrict__ cell,
                          float* __restrict__ Y, int E)
{
    int e = blockIdx.x * blockDim.x + threadIdx.x;
    if (e >= E) return;
    int s = src[e], d = dst[e];
    float cx = cell[0], cy = cell[4], cz = cell[8];
    float ex = pos[d*3+0] - pos[s*3+0];
    float ey = pos[d*3+1] - pos[s*3+1];
    float ez = pos[d*3+2] - pos[s*3+2];
    ex -= rintf(ex/cx)*cx;
    ey -= rintf(ey/cy)*cy;
    ez -= rintf(ez/cz)*cz;
    float len = fmaxf(sqrtf(ex*ex + ey*ey + ez*ez), 1e-8f);
    float x = ex/len, y = ey/len, z = ez/len;
    float x2 = x*x, y2 = y*y, z2 = z*z;
    float o[16];
    o[0]  = 0.28209479177387814f;
    o[1]  = 0.4886025119029199f*y;
    o[2]  = 0.4886025119029199f*z;
    o[3]  = 0.4886025119029199f*x;
    o[4]  = 1.0925484305920792f*x*y;
    o[5]  = 1.0925484305920792f*y*z;
    o[6]  = 0.31539156525252005f*(3.0f*z2 - 1.0f);
    o[7]  = 1.0925484305920792f*x*z;
    o[8]  = 0.5462742152960396f*(x2 - y2);
    o[9]  = 0.5900435899266435f*y*(3.0f*x2 - y2);
    o[10] = 2.890611442640554f*x*y*z;
    o[11] = 0.4570457994644658f*y*(5.0f*z2 - 1.0f);
    o[12] = 0.3731763325901154f*z*(5.0f*z2 - 3.0f);
    o[13] = 0.4570457994644658f*x*(5.0f*z2 - 1.0f);
    o[14] = 1.445305721320277f*z*(x2 - y2);
    o[15] = 0.5900435899266435f*x*(x2 - 3.0f*y2);
    float4* Yo = (float4*)(Y + (size_t)e*16);
    Yo[0] = make_float4(o[0],o[1],o[2],o[3]);
    Yo[1] = make_float4(o[4],o[5],o[6],o[7]);
    Yo[2] = make_float4(o[8],o[9],o[10],o[11]);
    Yo[3] = make_float4(o[12],o[13],o[14],o[15]);
}

// K2: per-node tensor-product transform tf0[n, d*16+m] = sum_c emb[an[n]][c*16+m] * W0[l(m)][c][d]
__global__ __launch_bounds__(256) void k_tf(const float* __restrict__ emb,
                                            const int* __restrict__ an,
                                            const float* __restrict__ w0,
                                            float* __restrict__ tf, int N)
{
    __shared__ float nf[DF];
    __shared__ float w[4*32*32];
    int n = blockIdx.x;
    int t = threadIdx.x;
    int a = an[n];
    nf[t]       = emb[(size_t)a*DF + t];
    nf[t + 256] = emb[(size_t)a*DF + t + 256];
    for (int i = t; i < 4096; i += 256) w[i] = w0[i];
    __syncthreads();
    #pragma unroll
    for (int rep = 0; rep < 2; rep++) {
        int f = t + rep*256;
        int d = f >> 4, m = f & 15;
        int l = c_lidx[m];
        const float* wl = &w[l*1024 + d];
        float acc = 0.0f;
        #pragma unroll
        for (int c = 0; c < 32; c++) acc += nf[c*16 + m] * wl[c*32];
        tf[(size_t)n*DF + f] = acc;
    }
}

// K3: edge scatter  agg[dst] += Y[e,m] * tf[src, d*16+m]   (atomics)
__global__ __launch_bounds__(256) void k_scatter(const float* __restrict__ tf,
                                                 const float* __restrict__ Y,
                                                 const int* __restrict__ src,
                                                 const int* __restrict__ dst,
                                                 float* __restrict__ agg, int E)
{
    int t = threadIdx.x;
    int m = t & 15;
    for (int e = blockIdx.x; e < E; e += gridDim.x) {
        int s = src[e], d = dst[e];
        float y = Y[(size_t)e*16 + m];
        const float* tr = tf + (size_t)s*DF;
        float* ar = agg + (size_t)d*DF;
        atomicAdd(&ar[t],       tr[t]       * y);
        atomicAdd(&ar[t + 256], tr[t + 256] * y);
    }
}

// K4: nf1 = emb[an] + agg @ lin_w0 + lin_b0 ; also E1 += sum(nf1 * out_w)
#define BM 64
#define BN 64
#define BK 16
__global__ __launch_bounds__(256) void k_lin(const float* __restrict__ A,
                                             const float* __restrict__ B,
                                             const float* __restrict__ bias,
                                             const float* __restrict__ emb,
                                             const int* __restrict__ an,
                                             const float* __restrict__ outw,
                                             float* __restrict__ nf1,
                                             float* __restrict__ out, int N)
{
    __shared__ float As[BK][BM + 4];
    __shared__ float Bs[BK][BN + 4];
    int t = threadIdx.x;
    int tx = t & 15, ty = t >> 4;
    int Ms = blockIdx.y * BM, Ns = blockIdx.x * BN;
    float acc[4][4] = {};
    for (int k0 = 0; k0 < DF; k0 += BK) {
        {
            int r = t >> 2;
            int c = (t & 3) * 4;
            float4 v = make_float4(0,0,0,0);
            int row = Ms + r;
            if (row < N) v = *(const float4*)&A[(size_t)row*DF + k0 + c];
            As[c+0][r] = v.x; As[c+1][r] = v.y; As[c+2][r] = v.z; As[c+3][r] = v.w;
        }
        {
            int r = t >> 4;
            int c = (t & 15) * 4;
            float4 v = *(const float4*)&B[(size_t)(k0 + r)*DF + Ns + c];
            Bs[r][c+0] = v.x; Bs[r][c+1] = v.y; Bs[r][c+2] = v.z; Bs[r][c+3] = v.w;
        }
        __syncthreads();
        #pragma unroll
        for (int kk = 0; kk < BK; kk++) {
            float4 av = *(const float4*)&As[kk][ty*4];
            float4 bv = *(const float4*)&Bs[kk][tx*4];
            float a[4] = {av.x, av.y, av.z, av.w};
            float b[4] = {bv.x, bv.y, bv.z, bv.w};
            #pragma unroll
            for (int i = 0; i < 4; i++)
                #pragma unroll
                for (int j = 0; j < 4; j++)
                    acc[i][j] += a[i] * b[j];
        }
        __syncthreads();
    }
    float epart = 0.0f;
    #pragma unroll
    for (int i = 0; i < 4; i++) {
        int row = Ms + ty*4 + i;
        if (row < N) {
            int a = an[row];
            #pragma unroll
            for (int j = 0; j < 4; j++) {
                int col = Ns + tx*4 + j;
                float v = acc[i][j] + emb[(size_t)a*DF + col] + bias[col];
                nf1[(size_t)row*DF + col] = v;
                epart += v * outw[col];
            }
        }
    }
    __shared__ float red[256];
    red[t] = epart;
    __syncthreads();
    for (int s = 128; s > 0; s >>= 1) {
        if (t < s) red[t] += red[t + s];
        __syncthreads();
    }
    if (t == 0) atomicAdd(out, red[0]);
}

// K5: S2 = sum_e sum_m Y[e,m] * sum_c nf1[src, c*16+m] * u1[c*16+m]
__global__ __launch_bounds__(256) void k_s2(const float* __restrict__ nf1,
                                            const float* __restrict__ Y,
                                            const int* __restrict__ src,
                                            const float* __restrict__ u1,
                                            float* __restrict__ out, int E)
{
    int t = threadIdx.x;
    int lane = t & 63;
    int wid = blockIdx.x * 4 + (t >> 6);
    int nw = gridDim.x * 4;
    int f0 = lane * 8;
    float u[8];
    #pragma unroll
    for (int j = 0; j < 8; j++) u[j] = u1[f0 + j];
    int ybase = f0 & 15;  // 0 or 8
    float part = 0.0f;
    for (int e = wid; e < E; e += nw) {
        int s = src[e];
        const float4* nr = (const float4*)(nf1 + (size_t)s*DF + f0);
        float4 n0 = nr[0], n1 = nr[1];
        const float4* yr = (const float4*)(Y + (size_t)e*16 + ybase);
        float4 y0 = yr[0], y1 = yr[1];
        part += n0.x*u[0]*y0.x + n0.y*u[1]*y0.y + n0.z*u[2]*y0.z + n0.w*u[3]*y0.w
              + n1.x*u[4]*y1.x + n1.y*u[5]*y1.y + n1.z*u[6]*y1.z + n1.w*u[7]*y1.w;
    }
    #pragma unroll
    for (int off = 32; off > 0; off >>= 1) part += __shfl_down(part, off, 64);
    __shared__ float red[4];
    if (lane == 0) red[t >> 6] = part;
    __syncthreads();
    if (t == 0) atomicAdd(out, red[0] + red[1] + red[2] + red[3]);
}

// K_pre: v = lin_w1 @ out_w ; u1[c*16+m] = sum_d tp_w1[l(m)][c][d]*v[d*16+m];
//        out += N*(lin_b1 . out_w + out_b)
__global__ __launch_bounds__(512) void k_pre(const float* __restrict__ lw1,
                                             const float* __restrict__ tw1,
                                             const float* __restrict__ lb1,
                                             const float* __restrict__ ow,
                                             const float* __restrict__ ob,
                                             float* __restrict__ u1,
                                             float* __restrict__ out, int N)
{
    __shared__ float v[DF];
    __shared__ float ows[DF];
    __shared__ float red[DF];
    int t = threadIdx.x;
    ows[t] = ow[t];
    __syncthreads();
    float acc = 0.0f;
    for (int k = 0; k < DF; k++) acc += lw1[(size_t)t*DF + k] * ows[k];
    v[t] = acc;
    __syncthreads();
    int c = t >> 4, m = t & 15, l = c_lidx[m];
    float u = 0.0f;
    #pragma unroll
    for (int d = 0; d < 32; d++) u += tw1[l*1024 + c*32 + d] * v[d*16 + m];
    u1[t] = u;
    red[t] = lb1[t] * ows[t];
    __syncthreads();
    for (int s = 256; s > 0; s >>= 1) {
        if (t < s) red[t] += red[t + s];
        __syncthreads();
    }
    if (t == 0) out[0] += (float)N * (red[0] + ob[0]);
}

extern "C" void kernel_launch(void* const* d_in, const int* in_sizes, int n_in,
                              void* d_out, int out_size, void* d_ws, size_t ws_size,
                              hipStream_t stream)
{
    const float* pos  = (const float*)d_in[0];
    const float* cell = (const float*)d_in[1];
    const int*   an   = (const int*)d_in[2];
    const int*   ei   = (const int*)d_in[3];
    const float* emb  = (const float*)d_in[4];
    const float* tw0  = (const float*)d_in[5];
    const float* lw0  = (const float*)d_in[6];
    const float* lb0  = (const float*)d_in[7];
    const float* tw1  = (const float*)d_in[8];
    const float* lw1  = (const float*)d_in[9];
    const float* lb1  = (const float*)d_in[10];
    const float* ow   = (const float*)d_in[11];
    const float* ob   = (const float*)d_in[12];
    int N = in_sizes[0] / 3;
    int E = in_sizes[3] / 2;
    const int* src = ei;
    const int* dst = ei + E;

    char* ws = (char*)d_ws;
    size_t off = 0;
    auto alloc = [&](size_t bytes) { void* p = ws + off; off += (bytes + 255) / 256 * 256; return p; };
    float* Y   = (float*)alloc((size_t)E * 16 * 4);
    float* tf0 = (float*)alloc((size_t)N * DF * 4);   // later reused as nf1
    float* agg = (float*)alloc((size_t)N * DF * 4);
    float* u1  = (float*)alloc(DF * 4);
    float* nf1 = tf0;  // tf0 is dead after k_scatter; alias

    float* out = (float*)d_out;

    hipMemsetAsync(out, 0, sizeof(float), stream);
    hipMemsetAsync(agg, 0, (size_t)N * DF * 4, stream);

    k_pre<<<1, 512, 0, stream>>>(lw1, tw1, lb1, ow, ob, u1, out, N);
    k_edge_sh<<<(E + 255) / 256, 256, 0, stream>>>(pos, src, dst, cell, Y, E);
    k_tf<<<N, 256, 0, stream>>>(emb, an, tw0, tf0, N);
    k_scatter<<<4096, 256, 0, stream>>>(tf0, Y, src, dst, agg, E);
    dim3 g4((DF + BN - 1) / BN, (N + BM - 1) / BM);
    k_lin<<<g4, 256, 0, stream>>>(agg, lw0, lb0, emb, an, ow, nf1, out, N);
    k_s2<<<2048, 256, 0, stream>>>(nf1, Y, src, u1, out, E);
}

// Round 2
// 474.640 us; speedup vs baseline: 1.6563x; 1.6563x over previous
//
#include <hip/hip_runtime.h>
#include <math.h>

#define HCH 32
#define NIR 16
#define DF 512

__device__ __constant__ int c_lidx[16] = {0,1,1,1,2,2,2,2,2,3,3,3,3,3,3,3};

// K1: per-edge spherical harmonics Y[E][16]
__global__ void k_edge_sh(const float* __restrict__ pos,
                          const int* __restrict__ src,
                          const int* __restrict__ dst,
                          const float* __restrict__ cell,
                          float* __restrict__ Y, int E)
{
    int e = blockIdx.x * blockDim.x + threadIdx.x;
    if (e >= E) return;
    int s = src[e], d = dst[e];
    float cx = cell[0], cy = cell[4], cz = cell[8];
    float ex = pos[d*3+0] - pos[s*3+0];
    float ey = pos[d*3+1] - pos[s*3+1];
    float ez = pos[d*3+2] - pos[s*3+2];
    ex -= rintf(ex/cx)*cx;
    ey -= rintf(ey/cy)*cy;
    ez -= rintf(ez/cz)*cz;
    float len = fmaxf(sqrtf(ex*ex + ey*ey + ez*ez), 1e-8f);
    float x = ex/len, y = ey/len, z = ez/len;
    float x2 = x*x, y2 = y*y, z2 = z*z;
    float o[16];
    o[0]  = 0.28209479177387814f;
    o[1]  = 0.4886025119029199f*y;
    o[2]  = 0.4886025119029199f*z;
    o[3]  = 0.4886025119029199f*x;
    o[4]  = 1.0925484305920792f*x*y;
    o[5]  = 1.0925484305920792f*y*z;
    o[6]  = 0.31539156525252005f*(3.0f*z2 - 1.0f);
    o[7]  = 1.0925484305920792f*x*z;
    o[8]  = 0.5462742152960396f*(x2 - y2);
    o[9]  = 0.5900435899266435f*y*(3.0f*x2 - y2);
    o[10] = 2.890611442640554f*x*y*z;
    o[11] = 0.4570457994644658f*y*(5.0f*z2 - 1.0f);
    o[12] = 0.3731763325901154f*z*(5.0f*z2 - 3.0f);
    o[13] = 0.4570457994644658f*x*(5.0f*z2 - 1.0f);
    o[14] = 1.445305721320277f*z*(x2 - y2);
    o[15] = 0.5900435899266435f*x*(x2 - 3.0f*y2);
    float4* Yo = (float4*)(Y + (size_t)e*16);
    Yo[0] = make_float4(o[0],o[1],o[2],o[3]);
    Yo[1] = make_float4(o[4],o[5],o[6],o[7]);
    Yo[2] = make_float4(o[8],o[9],o[10],o[11]);
    Yo[3] = make_float4(o[12],o[13],o[14],o[15]);
}

// K2: per-node tensor-product transform tf0[n, d*16+m] = sum_c emb[an[n]][c*16+m] * W0[l(m)][c][d]
__global__ __launch_bounds__(256) void k_tf(const float* __restrict__ emb,
                                            const int* __restrict__ an,
                                            const float* __restrict__ w0,
                                            float* __restrict__ tf, int N)
{
    __shared__ float nf[DF];
    __shared__ float w[4*32*32];
    int n = blockIdx.x;
    int t = threadIdx.x;
    int a = an[n];
    nf[t]       = emb[(size_t)a*DF + t];
    nf[t + 256] = emb[(size_t)a*DF + t + 256];
    for (int i = t; i < 4096; i += 256) w[i] = w0[i];
    __syncthreads();
    #pragma unroll
    for (int rep = 0; rep < 2; rep++) {
        int f = t + rep*256;
        int d = f >> 4, m = f & 15;
        int l = c_lidx[m];
        const float* wl = &w[l*1024 + d];
        float acc = 0.0f;
        #pragma unroll
        for (int c = 0; c < 32; c++) acc += nf[c*16 + m] * wl[c*32];
        tf[(size_t)n*DF + f] = acc;
    }
}

// ---- CSR build (by dst) ----
__global__ void k_hist(const int* __restrict__ dst, int* __restrict__ cnt, int E)
{
    int e = blockIdx.x * blockDim.x + threadIdx.x;
    if (e < E) atomicAdd(&cnt[dst[e]], 1);
}

// single-block exclusive scan of cnt[0..N) -> rp[0..N]; cnt becomes cursor (= rp[i])
__global__ __launch_bounds__(1024) void k_scan(int* __restrict__ cnt,
                                               int* __restrict__ rp, int N, int E)
{
    __shared__ int wsum[16];
    __shared__ int sh_total;
    __shared__ int sh_carry;
    int t = threadIdx.x;
    int lane = t & 63, wv = t >> 6;
    if (t == 0) sh_carry = 0;
    __syncthreads();
    for (int base = 0; base < N; base += 1024) {
        int i = base + t;
        int orig = (i < N) ? cnt[i] : 0;
        int v = orig;
        #pragma unroll
        for (int off = 1; off < 64; off <<= 1) {
            int x = __shfl_up(v, off, 64);
            if (lane >= off) v += x;
        }
        if (lane == 63) wsum[wv] = v;
        __syncthreads();
        if (t < 16) {
            int x = wsum[t];
            int incl = x;
            #pragma unroll
            for (int off = 1; off < 16; off <<= 1) {
                int y = __shfl_up(incl, off, 16);
                if (t >= off) incl += y;
            }
            wsum[t] = incl - x;            // exclusive wave offset
            if (t == 15) sh_total = incl;  // chunk total
        }
        __syncthreads();
        int excl = sh_carry + wsum[wv] + (v - orig);
        if (i < N) { rp[i] = excl; cnt[i] = excl; }
        __syncthreads();
        if (t == 0) sh_carry += sh_total;
        __syncthreads();
    }
    if (t == 0) rp[N] = E;
}

__global__ void k_fill(const int* __restrict__ src, const int* __restrict__ dst,
                       int* __restrict__ cur, int* __restrict__ eA,
                       int* __restrict__ sA, int E)
{
    int e = blockIdx.x * blockDim.x + threadIdx.x;
    if (e >= E) return;
    int d = dst[e];
    int p = atomicAdd(&cur[d], 1);
    eA[p] = e;
    sA[p] = src[e];
}

// K3': CSR aggregation, one wave per destination node, no atomics.
// agg[n, f] = sum_{edges into n} Y[e, f&15] * tf[src[e], f]
__global__ __launch_bounds__(256) void k_agg(const float* __restrict__ tf,
                                             const float* __restrict__ Y,
                                             const int* __restrict__ rp,
                                             const int* __restrict__ eA,
                                             const int* __restrict__ sA,
                                             float* __restrict__ agg, int N)
{
    int wid = blockIdx.x * 4 + (threadIdx.x >> 6);
    if (wid >= N) return;
    int lane = threadIdx.x & 63;
    int f0 = lane * 8;
    int yoff = f0 & 15;  // 0 or 8
    int beg = rp[wid], end = rp[wid + 1];
    float acc[8] = {0,0,0,0,0,0,0,0};
    int i = beg;
    for (; i + 1 < end; i += 2) {
        int e0 = eA[i],   s0 = sA[i];
        int e1 = eA[i+1], s1 = sA[i+1];
        const float4* r0 = (const float4*)(tf + (size_t)s0*DF + f0);
        const float4* r1 = (const float4*)(tf + (size_t)s1*DF + f0);
        float4 a0 = r0[0], b0 = r0[1];
        float4 a1 = r1[0], b1 = r1[1];
        const float4* q0 = (const float4*)(Y + (size_t)e0*16 + yoff);
        const float4* q1 = (const float4*)(Y + (size_t)e1*16 + yoff);
        float4 y00 = q0[0], y01 = q0[1];
        float4 y10 = q1[0], y11 = q1[1];
        acc[0] += a0.x*y00.x + a1.x*y10.x;
        acc[1] += a0.y*y00.y + a1.y*y10.y;
        acc[2] += a0.z*y00.z + a1.z*y10.z;
        acc[3] += a0.w*y00.w + a1.w*y10.w;
        acc[4] += b0.x*y01.x + b1.x*y11.x;
        acc[5] += b0.y*y01.y + b1.y*y11.y;
        acc[6] += b0.z*y01.z + b1.z*y11.z;
        acc[7] += b0.w*y01.w + b1.w*y11.w;
    }
    if (i < end) {
        int e0 = eA[i], s0 = sA[i];
        const float4* r0 = (const float4*)(tf + (size_t)s0*DF + f0);
        float4 a0 = r0[0], b0 = r0[1];
        const float4* q0 = (const float4*)(Y + (size_t)e0*16 + yoff);
        float4 y00 = q0[0], y01 = q0[1];
        acc[0] += a0.x*y00.x; acc[1] += a0.y*y00.y;
        acc[2] += a0.z*y00.z; acc[3] += a0.w*y00.w;
        acc[4] += b0.x*y01.x; acc[5] += b0.y*y01.y;
        acc[6] += b0.z*y01.z; acc[7] += b0.w*y01.w;
    }
    float4* ao = (float4*)(agg + (size_t)wid*DF + f0);
    ao[0] = make_float4(acc[0], acc[1], acc[2], acc[3]);
    ao[1] = make_float4(acc[4], acc[5], acc[6], acc[7]);
}

// K4: nf1 = emb[an] + agg @ lin_w0 + lin_b0 ; also E1 += sum(nf1 * out_w)
#define BM 64
#define BN 64
#define BK 16
__global__ __launch_bounds__(256) void k_lin(const float* __restrict__ A,
                                             const float* __restrict__ B,
                                             const float* __restrict__ bias,
                                             const float* __restrict__ emb,
                                             const int* __restrict__ an,
                                             const float* __restrict__ outw,
                                             float* __restrict__ nf1,
                                             float* __restrict__ out, int N)
{
    __shared__ float As[BK][BM + 4];
    __shared__ float Bs[BK][BN + 4];
    int t = threadIdx.x;
    int tx = t & 15, ty = t >> 4;
    int Ms = blockIdx.y * BM, Ns = blockIdx.x * BN;
    float acc[4][4] = {};
    for (int k0 = 0; k0 < DF; k0 += BK) {
        {
            int r = t >> 2;
            int c = (t & 3) * 4;
            float4 v = make_float4(0,0,0,0);
            int row = Ms + r;
            if (row < N) v = *(const float4*)&A[(size_t)row*DF + k0 + c];
            As[c+0][r] = v.x; As[c+1][r] = v.y; As[c+2][r] = v.z; As[c+3][r] = v.w;
        }
        {
            int r = t >> 4;
            int c = (t & 15) * 4;
            float4 v = *(const float4*)&B[(size_t)(k0 + r)*DF + Ns + c];
            Bs[r][c+0] = v.x; Bs[r][c+1] = v.y; Bs[r][c+2] = v.z; Bs[r][c+3] = v.w;
        }
        __syncthreads();
        #pragma unroll
        for (int kk = 0; kk < BK; kk++) {
            float4 av = *(const float4*)&As[kk][ty*4];
            float4 bv = *(const float4*)&Bs[kk][tx*4];
            float a[4] = {av.x, av.y, av.z, av.w};
            float b[4] = {bv.x, bv.y, bv.z, bv.w};
            #pragma unroll
            for (int i = 0; i < 4; i++)
                #pragma unroll
                for (int j = 0; j < 4; j++)
                    acc[i][j] += a[i] * b[j];
        }
        __syncthreads();
    }
    float epart = 0.0f;
    #pragma unroll
    for (int i = 0; i < 4; i++) {
        int row = Ms + ty*4 + i;
        if (row < N) {
            int a = an[row];
            #pragma unroll
            for (int j = 0; j < 4; j++) {
                int col = Ns + tx*4 + j;
                float v = acc[i][j] + emb[(size_t)a*DF + col] + bias[col];
                nf1[(size_t)row*DF + col] = v;
                epart += v * outw[col];
            }
        }
    }
    __shared__ float red[256];
    red[t] = epart;
    __syncthreads();
    for (int s = 128; s > 0; s >>= 1) {
        if (t < s) red[t] += red[t + s];
        __syncthreads();
    }
    if (t == 0) atomicAdd(out, red[0]);
}

// K5a: yacc[n, m] = sum_{e: src[e]=n} Y[e, m]   (atomics, 1.25 MB L2-resident)
__global__ void k_yacc(const float* __restrict__ Y, const int* __restrict__ src,
                       float* __restrict__ yacc, int E)
{
    int g = blockIdx.x * blockDim.x + threadIdx.x;
    if (g >= E * 16) return;
    int e = g >> 4, m = g & 15;
    atomicAdd(&yacc[(size_t)src[e]*16 + m], Y[g]);
}

// K5b: S2 = sum_n sum_f nf1[n,f] * u1[f] * yacc[n, f&15]
__global__ __launch_bounds__(256) void k_w(const float* __restrict__ nf1,
                                           const float* __restrict__ yacc,
                                           const float* __restrict__ u1,
                                           float* __restrict__ out, int N)
{
    int t = threadIdx.x;
    int lane = t & 63;
    int wid = blockIdx.x * 4 + (t >> 6);
    int nw = gridDim.x * 4;
    int f0 = lane * 8, yoff = f0 & 15;
    float u[8];
    #pragma unroll
    for (int j = 0; j < 8; j++) u[j] = u1[f0 + j];
    float sum = 0.0f;
    for (int n = wid; n < N; n += nw) {
        const float4* nr = (const float4*)(nf1 + (size_t)n*DF + f0);
        float4 a = nr[0], b = nr[1];
        const float4* yr = (const float4*)(yacc + (size_t)n*16 + yoff);
        float4 y0 = yr[0], y1 = yr[1];
        sum += a.x*u[0]*y0.x + a.y*u[1]*y0.y + a.z*u[2]*y0.z + a.w*u[3]*y0.w
             + b.x*u[4]*y1.x + b.y*u[5]*y1.y + b.z*u[6]*y1.z + b.w*u[7]*y1.w;
    }
    #pragma unroll
    for (int off = 32; off > 0; off >>= 1) sum += __shfl_down(sum, off, 64);
    if (lane == 0) atomicAdd(out, sum);
}

// K_pre: v = lin_w1 @ out_w ; u1[c*16+m] = sum_d tp_w1[l(m)][c][d]*v[d*16+m];
//        out += N*(lin_b1 . out_w + out_b)
__global__ __launch_bounds__(512) void k_pre(const float* __restrict__ lw1,
                                             const float* __restrict__ tw1,
                                             const float* __restrict__ lb1,
                                             const float* __restrict__ ow,
                                             const float* __restrict__ ob,
                                             float* __restrict__ u1,
                                             float* __restrict__ out, int N)
{
    __shared__ float v[DF];
    __shared__ float ows[DF];
    __shared__ float red[DF];
    int t = threadIdx.x;
    ows[t] = ow[t];
    __syncthreads();
    float acc = 0.0f;
    for (int k = 0; k < DF; k++) acc += lw1[(size_t)t*DF + k] * ows[k];
    v[t] = acc;
    __syncthreads();
    int c = t >> 4, m = t & 15, l = c_lidx[m];
    float u = 0.0f;
    #pragma unroll
    for (int d = 0; d < 32; d++) u += tw1[l*1024 + c*32 + d] * v[d*16 + m];
    u1[t] = u;
    red[t] = lb1[t] * ows[t];
    __syncthreads();
    for (int s = 256; s > 0; s >>= 1) {
        if (t < s) red[t] += red[t + s];
        __syncthreads();
    }
    if (t == 0) out[0] += (float)N * (red[0] + ob[0]);
}

extern "C" void kernel_launch(void* const* d_in, const int* in_sizes, int n_in,
                              void* d_out, int out_size, void* d_ws, size_t ws_size,
                              hipStream_t stream)
{
    const float* pos  = (const float*)d_in[0];
    const float* cell = (const float*)d_in[1];
    const int*   an   = (const int*)d_in[2];
    const int*   ei   = (const int*)d_in[3];
    const float* emb  = (const float*)d_in[4];
    const float* tw0  = (const float*)d_in[5];
    const float* lw0  = (const float*)d_in[6];
    const float* lb0  = (const float*)d_in[7];
    const float* tw1  = (const float*)d_in[8];
    const float* lw1  = (const float*)d_in[9];
    const float* lb1  = (const float*)d_in[10];
    const float* ow   = (const float*)d_in[11];
    const float* ob   = (const float*)d_in[12];
    int N = in_sizes[0] / 3;
    int E = in_sizes[3] / 2;
    const int* src = ei;
    const int* dst = ei + E;

    char* ws = (char*)d_ws;
    size_t off = 0;
    auto alloc = [&](size_t bytes) { void* p = ws + off; off += (bytes + 255) / 256 * 256; return p; };
    float* Y    = (float*)alloc((size_t)E * 16 * 4);
    float* tf0  = (float*)alloc((size_t)N * DF * 4);   // later reused as nf1
    float* agg  = (float*)alloc((size_t)N * DF * 4);
    float* u1   = (float*)alloc(DF * 4);
    float* yacc = (float*)alloc((size_t)N * 16 * 4);
    int*   cnt  = (int*)alloc((size_t)N * 4);          // histogram, then CSR cursor
    int*   rp   = (int*)alloc((size_t)(N + 1) * 4);
    int*   eA   = (int*)alloc((size_t)E * 4);
    int*   sA   = (int*)alloc((size_t)E * 4);
    float* nf1  = tf0;  // tf0 dead after k_agg; alias

    float* out = (float*)d_out;

    hipMemsetAsync(out, 0, sizeof(float), stream);
    hipMemsetAsync(cnt, 0, (size_t)N * 4, stream);
    hipMemsetAsync(yacc, 0, (size_t)N * 16 * 4, stream);

    k_pre<<<1, 512, 0, stream>>>(lw1, tw1, lb1, ow, ob, u1, out, N);
    k_edge_sh<<<(E + 255) / 256, 256, 0, stream>>>(pos, src, dst, cell, Y, E);
    k_hist<<<(E + 255) / 256, 256, 0, stream>>>(dst, cnt, E);
    k_scan<<<1, 1024, 0, stream>>>(cnt, rp, N, E);
    k_fill<<<(E + 255) / 256, 256, 0, stream>>>(src, dst, cnt, eA, sA, E);
    k_tf<<<N, 256, 0, stream>>>(emb, an, tw0, tf0, N);
    k_agg<<<(N + 3) / 4, 256, 0, stream>>>(tf0, Y, rp, eA, sA, agg, N);
    dim3 g4((DF + BN - 1) / BN, (N + BM - 1) / BM);
    k_lin<<<g4, 256, 0, stream>>>(agg, lw0, lb0, emb, an, ow, nf1, out, N);
    k_yacc<<<(E * 16 + 255) / 256, 256, 0, stream>>>(Y, src, yacc, E);
    k_w<<<512, 256, 0, stream>>>(nf1, yacc, u1, out, N);
}

// Round 3
// 333.462 us; speedup vs baseline: 2.3575x; 1.4234x over previous
//
#include <hip/hip_runtime.h>
#include <math.h>

#define DF 512

typedef __attribute__((ext_vector_type(8))) short bf16x8;
typedef __attribute__((ext_vector_type(4))) float f32x4;
typedef __attribute__((ext_vector_type(4))) int int4v;

__device__ __constant__ int c_lidx[16] = {0,1,1,1,2,2,2,2,2,3,3,3,3,3,3,3};

__device__ inline float bf2f(unsigned short s) {
    union { unsigned int u; float f; } x;
    x.u = ((unsigned int)s) << 16;
    return x.f;
}
__device__ inline unsigned short f2bf(float f) {
    union { float f; unsigned int u; } x; x.f = f;
    unsigned int r = x.u + 0x7fffu + ((x.u >> 16) & 1u);
    return (unsigned short)(r >> 16);
}

// K1: per-edge spherical harmonics Y[E][16]
__global__ void k_edge_sh(const float* __restrict__ pos,
                          const int* __restrict__ src,
                          const int* __restrict__ dst,
                          const float* __restrict__ cell,
                          float* __restrict__ Y, int E)
{
    int e = blockIdx.x * blockDim.x + threadIdx.x;
    if (e >= E) return;
    int s = src[e], d = dst[e];
    float cx = cell[0], cy = cell[4], cz = cell[8];
    float ex = pos[d*3+0] - pos[s*3+0];
    float ey = pos[d*3+1] - pos[s*3+1];
    float ez = pos[d*3+2] - pos[s*3+2];
    ex -= rintf(ex/cx)*cx;
    ey -= rintf(ey/cy)*cy;
    ez -= rintf(ez/cz)*cz;
    float len = fmaxf(sqrtf(ex*ex + ey*ey + ez*ez), 1e-8f);
    float x = ex/len, y = ey/len, z = ez/len;
    float x2 = x*x, y2 = y*y, z2 = z*z;
    float o[16];
    o[0]  = 0.28209479177387814f;
    o[1]  = 0.4886025119029199f*y;
    o[2]  = 0.4886025119029199f*z;
    o[3]  = 0.4886025119029199f*x;
    o[4]  = 1.0925484305920792f*x*y;
    o[5]  = 1.0925484305920792f*y*z;
    o[6]  = 0.31539156525252005f*(3.0f*z2 - 1.0f);
    o[7]  = 1.0925484305920792f*x*z;
    o[8]  = 0.5462742152960396f*(x2 - y2);
    o[9]  = 0.5900435899266435f*y*(3.0f*x2 - y2);
    o[10] = 2.890611442640554f*x*y*z;
    o[11] = 0.4570457994644658f*y*(5.0f*z2 - 1.0f);
    o[12] = 0.3731763325901154f*z*(5.0f*z2 - 3.0f);
    o[13] = 0.4570457994644658f*x*(5.0f*z2 - 1.0f);
    o[14] = 1.445305721320277f*z*(x2 - y2);
    o[15] = 0.5900435899266435f*x*(x2 - 3.0f*y2);
    float4* Yo = (float4*)(Y + (size_t)e*16);
    Yo[0] = make_float4(o[0],o[1],o[2],o[3]);
    Yo[1] = make_float4(o[4],o[5],o[6],o[7]);
    Yo[2] = make_float4(o[8],o[9],o[10],o[11]);
    Yo[3] = make_float4(o[12],o[13],o[14],o[15]);
}

// K2: tf[n, d*16+m] = bf16( sum_c emb[an[n]][c*16+m] * W0[l(m)][c][d] )
__global__ __launch_bounds__(256) void k_tf(const float* __restrict__ emb,
                                            const int* __restrict__ an,
                                            const float* __restrict__ w0,
                                            unsigned short* __restrict__ tf, int N)
{
    __shared__ float nf[DF];
    __shared__ float w[4*32*32];
    int n = blockIdx.x;
    int t = threadIdx.x;
    int a = an[n];
    nf[t]       = emb[(size_t)a*DF + t];
    nf[t + 256] = emb[(size_t)a*DF + t + 256];
    for (int i = t; i < 4096; i += 256) w[i] = w0[i];
    __syncthreads();
    #pragma unroll
    for (int rep = 0; rep < 2; rep++) {
        int f = t + rep*256;
        int d = f >> 4, m = f & 15;
        int l = c_lidx[m];
        const float* wl = &w[l*1024 + d];
        float acc = 0.0f;
        #pragma unroll
        for (int c = 0; c < 32; c++) acc += nf[c*16 + m] * wl[c*32];
        tf[(size_t)n*DF + f] = f2bf(acc);
    }
}

// ---- CSR build (by dst) ----
__global__ void k_hist(const int* __restrict__ dst, int* __restrict__ cnt, int E)
{
    int e = blockIdx.x * blockDim.x + threadIdx.x;
    if (e < E) atomicAdd(&cnt[dst[e]], 1);
}

__global__ __launch_bounds__(1024) void k_scan(int* __restrict__ cnt,
                                               int* __restrict__ rp, int N, int E)
{
    __shared__ int wsum[16];
    __shared__ int sh_total;
    __shared__ int sh_carry;
    int t = threadIdx.x;
    int lane = t & 63, wv = t >> 6;
    if (t == 0) sh_carry = 0;
    __syncthreads();
    for (int base = 0; base < N; base += 1024) {
        int i = base + t;
        int orig = (i < N) ? cnt[i] : 0;
        int v = orig;
        #pragma unroll
        for (int off = 1; off < 64; off <<= 1) {
            int x = __shfl_up(v, off, 64);
            if (lane >= off) v += x;
        }
        if (lane == 63) wsum[wv] = v;
        __syncthreads();
        if (t < 16) {
            int x = wsum[t];
            int incl = x;
            #pragma unroll
            for (int off = 1; off < 16; off <<= 1) {
                int y = __shfl_up(incl, off, 16);
                if (t >= off) incl += y;
            }
            wsum[t] = incl - x;
            if (t == 15) sh_total = incl;
        }
        __syncthreads();
        int excl = sh_carry + wsum[wv] + (v - orig);
        if (i < N) { rp[i] = excl; cnt[i] = excl; }
        __syncthreads();
        if (t == 0) sh_carry += sh_total;
        __syncthreads();
    }
    if (t == 0) rp[N] = E;
}

__global__ void k_fill(const int* __restrict__ src, const int* __restrict__ dst,
                       int* __restrict__ cur, int* __restrict__ eA,
                       int* __restrict__ sA, int E)
{
    int e = blockIdx.x * blockDim.x + threadIdx.x;
    if (e >= E) return;
    int d = dst[e];
    int p = atomicAdd(&cur[d], 1);
    eA[p] = e;
    sA[p] = src[e];
}

// K3: CSR aggregation, one wave per destination node.
// aggbf[n, f] = bf16( sum_{edges into n} Y[e, f&15] * tf[src[e], f] )
__device__ inline void agg_edge(const unsigned short* __restrict__ tf,
                                const float* __restrict__ Y,
                                int e, int s, int f0, int yoff, float* acc)
{
    bf16x8 v = *(const bf16x8*)(tf + (size_t)s*DF + f0);
    const float4* q = (const float4*)(Y + (size_t)e*16 + yoff);
    float4 y0 = q[0], y1 = q[1];
    acc[0] += bf2f((unsigned short)v[0])*y0.x;
    acc[1] += bf2f((unsigned short)v[1])*y0.y;
    acc[2] += bf2f((unsigned short)v[2])*y0.z;
    acc[3] += bf2f((unsigned short)v[3])*y0.w;
    acc[4] += bf2f((unsigned short)v[4])*y1.x;
    acc[5] += bf2f((unsigned short)v[5])*y1.y;
    acc[6] += bf2f((unsigned short)v[6])*y1.z;
    acc[7] += bf2f((unsigned short)v[7])*y1.w;
}

__global__ __launch_bounds__(256) void k_agg(const unsigned short* __restrict__ tf,
                                             const float* __restrict__ Y,
                                             const int* __restrict__ rp,
                                             const int* __restrict__ eA,
                                             const int* __restrict__ sA,
                                             unsigned short* __restrict__ aggbf, int N)
{
    int wid = blockIdx.x * 4 + (threadIdx.x >> 6);
    if (wid >= N) return;
    int lane = threadIdx.x & 63;
    int f0 = lane * 8;
    int yoff = f0 & 15;
    int beg = rp[wid], end = rp[wid + 1];
    float acc[8] = {0,0,0,0,0,0,0,0};
    int i = beg;
    for (; i + 1 < end; i += 2) {
        agg_edge(tf, Y, eA[i],   sA[i],   f0, yoff, acc);
        agg_edge(tf, Y, eA[i+1], sA[i+1], f0, yoff, acc);
    }
    if (i < end) agg_edge(tf, Y, eA[i], sA[i], f0, yoff, acc);
    bf16x8 o;
    #pragma unroll
    for (int j = 0; j < 8; j++) o[j] = (short)f2bf(acc[j]);
    *(bf16x8*)(aggbf + (size_t)wid*DF + f0) = o;
}

// Bt[n][k] = bf16(lin_w0[k][n])
__global__ void k_convb(const float* __restrict__ w, unsigned short* __restrict__ bt)
{
    int idx = blockIdx.x * 256 + threadIdx.x;
    int n = idx >> 9, k = idx & 511;
    bt[idx] = f2bf(w[(size_t)k*DF + n]);
}

// K4: nf1 = emb[an] + A @ B + bias  (MFMA bf16);  out += sum(nf1*outw)
#define GBM 128
#define GBN 128
#define GBK 32
#define LDK 40
__global__ __launch_bounds__(256) void k_lin_mfma(const unsigned short* __restrict__ A,
                                                  const unsigned short* __restrict__ Bt,
                                                  const float* __restrict__ bias,
                                                  const float* __restrict__ emb,
                                                  const int* __restrict__ an,
                                                  const float* __restrict__ outw,
                                                  float* __restrict__ nf1,
                                                  float* __restrict__ out, int M)
{
    __shared__ unsigned short As[GBM][LDK];
    __shared__ unsigned short Bs[GBN][LDK];
    int t = threadIdx.x;
    int wave = t >> 6, lane = t & 63;
    int wr = wave >> 1, wc = wave & 1;
    int l15 = lane & 15, l16 = lane >> 4;
    int bm = blockIdx.y * GBM, bn = blockIdx.x * GBN;
    f32x4 acc[4][4] = {};
    for (int k0 = 0; k0 < DF; k0 += GBK) {
        #pragma unroll
        for (int i = 0; i < 2; i++) {
            int c = t + i*256;
            int row = c >> 2, ko = (c & 3) * 8;
            int4v av = *(const int4v*)&A[(size_t)(bm + row)*DF + k0 + ko];
            int4v bv = *(const int4v*)&Bt[(size_t)(bn + row)*DF + k0 + ko];
            *(int4v*)&As[row][ko] = av;
            *(int4v*)&Bs[row][ko] = bv;
        }
        __syncthreads();
        bf16x8 af[4], bfr[4];
        #pragma unroll
        for (int m = 0; m < 4; m++)
            af[m] = *(const bf16x8*)&As[wr*64 + m*16 + l15][l16*8];
        #pragma unroll
        for (int n = 0; n < 4; n++)
            bfr[n] = *(const bf16x8*)&Bs[wc*64 + n*16 + l15][l16*8];
        #pragma unroll
        for (int m = 0; m < 4; m++)
            #pragma unroll
            for (int n = 0; n < 4; n++)
                acc[m][n] = __builtin_amdgcn_mfma_f32_16x16x32_bf16(af[m], bfr[n], acc[m][n], 0, 0, 0);
        __syncthreads();
    }
    float epart = 0.0f;
    int crow0 = bm + wr*64, ccol0 = bn + wc*64;
    #pragma unroll
    for (int m = 0; m < 4; m++) {
        #pragma unroll
        for (int j = 0; j < 4; j++) {
            int row = crow0 + m*16 + l16*4 + j;
            if (row < M) {
                int a = an[row];
                #pragma unroll
                for (int n = 0; n < 4; n++) {
                    int col = ccol0 + n*16 + l15;
                    float v = acc[m][n][j] + emb[(size_t)a*DF + col] + bias[col];
                    nf1[(size_t)row*DF + col] = v;
                    epart += v * outw[col];
                }
            }
        }
    }
    __shared__ float red[256];
    red[t] = epart;
    __syncthreads();
    for (int s = 128; s > 0; s >>= 1) {
        if (t < s) red[t] += red[t + s];
        __syncthreads();
    }
    if (t == 0) atomicAdd(out, red[0]);
}

// K5a: yacc[n, m] = sum_{e: src[e]=n} Y[e, m]
__global__ void k_yacc(const float* __restrict__ Y, const int* __restrict__ src,
                       float* __restrict__ yacc, int E)
{
    int g = blockIdx.x * blockDim.x + threadIdx.x;
    if (g >= E * 16) return;
    int e = g >> 4, m = g & 15;
    atomicAdd(&yacc[(size_t)src[e]*16 + m], Y[g]);
}

// K5b: S2 = sum_n sum_f nf1[n,f] * u1[f] * yacc[n, f&15]
__global__ __launch_bounds__(256) void k_w(const float* __restrict__ nf1,
                                           const float* __restrict__ yacc,
                                           const float* __restrict__ u1,
                                           float* __restrict__ out, int N)
{
    int t = threadIdx.x;
    int lane = t & 63;
    int wid = blockIdx.x * 4 + (t >> 6);
    int nw = gridDim.x * 4;
    int f0 = lane * 8, yoff = f0 & 15;
    float u[8];
    #pragma unroll
    for (int j = 0; j < 8; j++) u[j] = u1[f0 + j];
    float sum = 0.0f;
    for (int n = wid; n < N; n += nw) {
        const float4* nr = (const float4*)(nf1 + (size_t)n*DF + f0);
        float4 a = nr[0], b = nr[1];
        const float4* yr = (const float4*)(yacc + (size_t)n*16 + yoff);
        float4 y0 = yr[0], y1 = yr[1];
        sum += a.x*u[0]*y0.x + a.y*u[1]*y0.y + a.z*u[2]*y0.z + a.w*u[3]*y0.w
             + b.x*u[4]*y1.x + b.y*u[5]*y1.y + b.z*u[6]*y1.z + b.w*u[7]*y1.w;
    }
    #pragma unroll
    for (int off = 32; off > 0; off >>= 1) sum += __shfl_down(sum, off, 64);
    if (lane == 0) atomicAdd(out, sum);
}

// K_pre: u1 and constant-bias energy term
__global__ __launch_bounds__(512) void k_pre(const float* __restrict__ lw1,
                                             const float* __restrict__ tw1,
                                             const float* __restrict__ lb1,
                                             const float* __restrict__ ow,
                                             const float* __restrict__ ob,
                                             float* __restrict__ u1,
                                             float* __restrict__ out, int N)
{
    __shared__ float v[DF];
    __shared__ float ows[DF];
    __shared__ float red[DF];
    int t = threadIdx.x;
    ows[t] = ow[t];
    __syncthreads();
    float acc = 0.0f;
    for (int k = 0; k < DF; k++) acc += lw1[(size_t)t*DF + k] * ows[k];
    v[t] = acc;
    __syncthreads();
    int c = t >> 4, m = t & 15, l = c_lidx[m];
    float u = 0.0f;
    #pragma unroll
    for (int d = 0; d < 32; d++) u += tw1[l*1024 + c*32 + d] * v[d*16 + m];
    u1[t] = u;
    red[t] = lb1[t] * ows[t];
    __syncthreads();
    for (int s = 256; s > 0; s >>= 1) {
        if (t < s) red[t] += red[t + s];
        __syncthreads();
    }
    if (t == 0) out[0] += (float)N * (red[0] + ob[0]);
}

extern "C" void kernel_launch(void* const* d_in, const int* in_sizes, int n_in,
                              void* d_out, int out_size, void* d_ws, size_t ws_size,
                              hipStream_t stream)
{
    const float* pos  = (const float*)d_in[0];
    const float* cell = (const float*)d_in[1];
    const int*   an   = (const int*)d_in[2];
    const int*   ei   = (const int*)d_in[3];
    const float* emb  = (const float*)d_in[4];
    const float* tw0  = (const float*)d_in[5];
    const float* lw0  = (const float*)d_in[6];
    const float* lb0  = (const float*)d_in[7];
    const float* tw1  = (const float*)d_in[8];
    const float* lw1  = (const float*)d_in[9];
    const float* lb1  = (const float*)d_in[10];
    const float* ow   = (const float*)d_in[11];
    const float* ob   = (const float*)d_in[12];
    int N = in_sizes[0] / 3;
    int E = in_sizes[3] / 2;
    const int* src = ei;
    const int* dst = ei + E;
    int Mpad = ((N + GBM - 1) / GBM) * GBM;

    char* ws = (char*)d_ws;
    size_t off = 0;
    auto alloc = [&](size_t bytes) { void* p = ws + off; off += (bytes + 255) / 256 * 256; return p; };

    // region1: Y | eA | sA | tf  overlapped with nf1 (nf1 written only after all are dead)
    size_t r1_start = off;
    float* Y            = (float*)alloc((size_t)E * 16 * 4);
    int*   eA           = (int*)alloc((size_t)E * 4);
    int*   sA           = (int*)alloc((size_t)E * 4);
    unsigned short* tf  = (unsigned short*)alloc((size_t)N * DF * 2);
    size_t r1_used = off - r1_start;
    size_t nf1_bytes = (size_t)N * DF * 4;
    if (r1_used < nf1_bytes) off = r1_start + (nf1_bytes + 255) / 256 * 256;
    float* nf1 = (float*)(ws + r1_start);

    unsigned short* aggbf = (unsigned short*)alloc((size_t)Mpad * DF * 2);
    unsigned short* Bt    = (unsigned short*)alloc((size_t)DF * DF * 2);
    float* u1   = (float*)alloc(DF * 4);
    float* yacc = (float*)alloc((size_t)N * 16 * 4);
    int*   cnt  = (int*)alloc((size_t)N * 4);
    int*   rp   = (int*)alloc((size_t)(N + 1) * 4);

    float* out = (float*)d_out;

    hipMemsetAsync(out, 0, sizeof(float), stream);
    hipMemsetAsync(cnt, 0, (size_t)N * 4, stream);
    hipMemsetAsync(yacc, 0, (size_t)N * 16 * 4, stream);
    if (Mpad > N)
        hipMemsetAsync(aggbf + (size_t)N * DF, 0, (size_t)(Mpad - N) * DF * 2, stream);

    k_pre<<<1, 512, 0, stream>>>(lw1, tw1, lb1, ow, ob, u1, out, N);
    k_edge_sh<<<(E + 255) / 256, 256, 0, stream>>>(pos, src, dst, cell, Y, E);
    k_hist<<<(E + 255) / 256, 256, 0, stream>>>(dst, cnt, E);
    k_scan<<<1, 1024, 0, stream>>>(cnt, rp, N, E);
    k_fill<<<(E + 255) / 256, 256, 0, stream>>>(src, dst, cnt, eA, sA, E);
    k_convb<<<(DF * DF) / 256, 256, 0, stream>>>(lw0, Bt);
    k_tf<<<N, 256, 0, stream>>>(emb, an, tw0, tf, N);
    k_agg<<<(N + 3) / 4, 256, 0, stream>>>(tf, Y, rp, eA, sA, aggbf, N);
    k_yacc<<<(E * 16 + 255) / 256, 256, 0, stream>>>(Y, src, yacc, E);
    // nf1 overwrites Y/eA/sA/tf (all dead now); aggbf/Bt live separately
    dim3 g4(DF / GBN, (N + GBM - 1) / GBM);
    k_lin_mfma<<<g4, 256, 0, stream>>>(aggbf, Bt, lb0, emb, an, ow, nf1, out, N);
    k_w<<<512, 256, 0, stream>>>(nf1, yacc, u1, out, N);
}